// Round 1
// baseline (539.018 us; speedup 1.0000x reference)
//
#include <hip/hip_runtime.h>

// ---------------------------------------------------------------------------
// SGC: out[b,i,f] = sum_{j!=i} (adj^4)[i,j] * rm[b,j,f]
// Restructured:
//   A2   = adj @ adj                      (bf16 MFMA, 4096^3)
//   T1   = A2 @ RM    (RM = rm as 4096x256)   -> stored transposed (256x4096)
//   T2   = A2 @ T1
//   d[i] = sum_j A2[i,j]*A2[j,i]
//   out  = T2 - d[i]*rm
// ---------------------------------------------------------------------------

typedef __attribute__((ext_vector_type(8))) __bf16 bf16x8;
typedef __attribute__((ext_vector_type(4))) float floatx4;
typedef __attribute__((ext_vector_type(4))) short short4v;

__device__ __forceinline__ unsigned short f32_to_bf16_bits(float f) {
  unsigned int u = __float_as_uint(f);
  u += 0x7FFFu + ((u >> 16) & 1u);   // round-to-nearest-even
  return (unsigned short)(u >> 16);
}
__device__ __forceinline__ float bf16_bits_to_f32(unsigned short s) {
  return __uint_as_float(((unsigned int)s) << 16);
}

// --- adj fp32 -> bf16 (row-major copy) -------------------------------------
__global__ __launch_bounds__(256) void k_f32_to_bf16(const float* __restrict__ in,
                                                     unsigned short* __restrict__ out,
                                                     int n4) {
  int i = blockIdx.x * 256 + threadIdx.x;
  if (i >= n4) return;
  const float4 v = ((const float4*)in)[i];
  short4v s;
  s.x = (short)f32_to_bf16_bits(v.x);
  s.y = (short)f32_to_bf16_bits(v.y);
  s.z = (short)f32_to_bf16_bits(v.z);
  s.w = (short)f32_to_bf16_bits(v.w);
  ((short4v*)out)[i] = s;
}

// --- adj fp32 -> bf16 transposed (AT[n][k] = adj[k][n]) --------------------
__global__ __launch_bounds__(256) void k_transpose_bf16(const float* __restrict__ in,
                                                        unsigned short* __restrict__ out) {
  __shared__ float tile[64][65];
  const int t = threadIdx.x;
  const int row0 = blockIdx.y * 64, col0 = blockIdx.x * 64;
  const int c4 = (t & 15) * 4;
  const int r = t >> 4;  // 0..15
  for (int rr = 0; rr < 64; rr += 16) {
    float4 v = *(const float4*)(in + (size_t)(row0 + r + rr) * 4096 + col0 + c4);
    tile[r + rr][c4 + 0] = v.x;
    tile[r + rr][c4 + 1] = v.y;
    tile[r + rr][c4 + 2] = v.z;
    tile[r + rr][c4 + 3] = v.w;
  }
  __syncthreads();
  for (int rr = 0; rr < 64; rr += 16) {
    const int orow = r + rr;  // index along original columns
    short4v s;
    s.x = (short)f32_to_bf16_bits(tile[c4 + 0][orow]);
    s.y = (short)f32_to_bf16_bits(tile[c4 + 1][orow]);
    s.z = (short)f32_to_bf16_bits(tile[c4 + 2][orow]);
    s.w = (short)f32_to_bf16_bits(tile[c4 + 3][orow]);
    *(short4v*)(out + (size_t)(col0 + orow) * 4096 + row0 + c4) = s;
  }
}

// --- RMT[c][j] = bf16(rm[b=c>>5, j, f=c&31]),  c in [0,256), j in [0,4096) --
__global__ __launch_bounds__(256) void k_build_rmt(const float* __restrict__ rm,
                                                   unsigned short* __restrict__ rmt) {
  const int idx = blockIdx.x * 256 + threadIdx.x;  // idx = c*4096 + j
  const int c = idx >> 12;
  const int j = idx & 4095;
  const int b = c >> 5, f = c & 31;
  rmt[idx] = f32_to_bf16_bits(rm[((size_t)b * 4096 + j) * 32 + f]);
}

__global__ __launch_bounds__(256) void k_zero_f32(float* __restrict__ p, int n) {
  int i = blockIdx.x * 256 + threadIdx.x;
  if (i < n) p[i] = 0.f;
}

// --- d[i] = sum_j A2[i,j]*A2[j,i]  (one 64x64 tile-pair per block) ----------
__global__ __launch_bounds__(256) void k_diag(const unsigned short* __restrict__ M2,
                                              float* __restrict__ d) {
  constexpr int P = 72;  // pitch: keeps int4 staging 16B-aligned, spreads banks
  __shared__ __align__(16) unsigned short t1[64 * P];
  __shared__ __align__(16) unsigned short t2[64 * P];
  __shared__ float red[256];
  const int I = blockIdx.x >> 6, J = blockIdx.x & 63;
  const int t = threadIdx.x;
  for (int c = t; c < 512; c += 256) {
    const int row = c >> 3, col = (c & 7) * 8;
    *(int4*)(t1 + row * P + col) =
        *(const int4*)(M2 + (size_t)(I * 64 + row) * 4096 + J * 64 + col);
    *(int4*)(t2 + row * P + col) =
        *(const int4*)(M2 + (size_t)(J * 64 + row) * 4096 + I * 64 + col);
  }
  __syncthreads();
  const int i = t & 63, q = t >> 6;
  float s = 0.f;
  #pragma unroll
  for (int jj = 0; jj < 16; ++jj) {
    const int j = q * 16 + jj;
    s += bf16_bits_to_f32(t1[i * P + j]) * bf16_bits_to_f32(t2[j * P + i]);
  }
  red[t] = s;
  __syncthreads();
  if (t < 64) {
    const float tot = red[t] + red[t + 64] + red[t + 128] + red[t + 192];
    atomicAdd(&d[I * 64 + t], tot);
  }
}

// --- GEMM: C[m][n] = sum_k A[m][k] * BT[n][k]   (bf16 in, fp32 acc) --------
// EPI 0: store bf16 C row-major (ldc = N)
// EPI 1: store bf16 C transposed (C[n][m], pitch M)
// EPI 2: fused out: out[(b*M+row)*32+f] = acc - d[row]*rm[...],  b=col>>5,f=col&31
template <int BM, int BN, int WM, int WN, int EPI>
__global__ __launch_bounds__(256) void k_gemm_bt(
    const unsigned short* __restrict__ A,   // M x K bf16 bits, row-major
    const unsigned short* __restrict__ BT,  // N x K bf16 bits, row-major
    void* __restrict__ Cout,
    const float* __restrict__ dvec,
    const float* __restrict__ rm,
    int M, int N, int K) {
  constexpr int BK = 64;
  constexpr int WROWS = BM / WM;
  constexpr int MI = WM / 16;
  constexpr int NI = WN / 16;
  __shared__ __align__(16) unsigned short smA[BM * BK];
  __shared__ __align__(16) unsigned short smB[BN * BK];

  const int tid = threadIdx.x;
  const int wave = tid >> 6;
  const int lane = tid & 63;
  const int quad = lane >> 4;
  const int l16 = lane & 15;
  const int wm = (wave % WROWS) * WM;
  const int wn = (wave / WROWS) * WN;
  const int m0 = blockIdx.x * BM;
  const int n0 = blockIdx.y * BN;

  floatx4 acc[MI][NI];
  #pragma unroll
  for (int i = 0; i < MI; ++i)
    #pragma unroll
    for (int j = 0; j < NI; ++j)
      acc[i][j] = floatx4{0.f, 0.f, 0.f, 0.f};

  for (int k0 = 0; k0 < K; k0 += BK) {
    #pragma unroll
    for (int c = 0; c < (BM * BK) / (8 * 256); ++c) {
      const int ch = c * 256 + tid;
      const int row = ch >> 3, col = (ch & 7) * 8;
      *(int4*)(smA + row * BK + col) =
          *(const int4*)(A + (size_t)(m0 + row) * K + k0 + col);
    }
    #pragma unroll
    for (int c = 0; c < (BN * BK) / (8 * 256); ++c) {
      const int ch = c * 256 + tid;
      const int row = ch >> 3, col = (ch & 7) * 8;
      *(int4*)(smB + row * BK + col) =
          *(const int4*)(BT + (size_t)(n0 + row) * K + k0 + col);
    }
    __syncthreads();
    #pragma unroll
    for (int kk = 0; kk < BK; kk += 32) {
      bf16x8 af[MI], bfr[NI];
      #pragma unroll
      for (int i = 0; i < MI; ++i)
        af[i] = *(const bf16x8*)(smA + (wm + i * 16 + l16) * BK + kk + quad * 8);
      #pragma unroll
      for (int j = 0; j < NI; ++j)
        bfr[j] = *(const bf16x8*)(smB + (wn + j * 16 + l16) * BK + kk + quad * 8);
      #pragma unroll
      for (int i = 0; i < MI; ++i)
        #pragma unroll
        for (int j = 0; j < NI; ++j)
          acc[i][j] = __builtin_amdgcn_mfma_f32_16x16x32_bf16(af[i], bfr[j],
                                                              acc[i][j], 0, 0, 0);
    }
    __syncthreads();
  }

  // epilogue: lane holds C[quad*4+r][l16] per 16x16 tile (verified m89/m91 layout)
  #pragma unroll
  for (int i = 0; i < MI; ++i) {
    #pragma unroll
    for (int j = 0; j < NI; ++j) {
      const int rowb = m0 + wm + i * 16 + quad * 4;
      const int col = n0 + wn + j * 16 + l16;
      if (EPI == 0) {
        unsigned short* C = (unsigned short*)Cout;
        #pragma unroll
        for (int r = 0; r < 4; ++r)
          C[(size_t)(rowb + r) * N + col] = f32_to_bf16_bits(acc[i][j][r]);
      } else if (EPI == 1) {
        unsigned short* C = (unsigned short*)Cout;  // N x M
        short4v s;
        s.x = (short)f32_to_bf16_bits(acc[i][j][0]);
        s.y = (short)f32_to_bf16_bits(acc[i][j][1]);
        s.z = (short)f32_to_bf16_bits(acc[i][j][2]);
        s.w = (short)f32_to_bf16_bits(acc[i][j][3]);
        *(short4v*)(C + (size_t)col * M + rowb) = s;
      } else {
        float* O = (float*)Cout;
        const int b = col >> 5, f = col & 31;
        #pragma unroll
        for (int r = 0; r < 4; ++r) {
          const int row = rowb + r;
          const size_t o = ((size_t)b * M + row) * 32 + f;
          O[o] = acc[i][j][r] - dvec[row] * rm[o];
        }
      }
    }
  }
}

extern "C" void kernel_launch(void* const* d_in, const int* in_sizes, int n_in,
                              void* d_out, int out_size, void* d_ws, size_t ws_size,
                              hipStream_t stream) {
  const float* rm = (const float*)d_in[0];   // (8, 4096, 32) fp32
  const float* adj = (const float*)d_in[1];  // (4096, 4096) fp32
  float* out = (float*)d_out;                // (8, 4096, 32) fp32
  char* ws = (char*)d_ws;

  unsigned short* Abf  = (unsigned short*)(ws);              // 32 MiB
  unsigned short* ATbf = (unsigned short*)(ws + 33554432);   // 32 MiB
  unsigned short* A2bf = (unsigned short*)(ws + 67108864);   // 32 MiB
  unsigned short* RMT  = (unsigned short*)(ws + 100663296);  // 2 MiB
  unsigned short* T1T  = (unsigned short*)(ws + 102760448);  // 2 MiB
  float* dvec          = (float*)(ws + 104857600);           // 16 KiB

  // prep
  k_f32_to_bf16<<<16384, 256, 0, stream>>>(adj, Abf, 4194304);
  k_transpose_bf16<<<dim3(64, 64), 256, 0, stream>>>(adj, ATbf);
  k_build_rmt<<<4096, 256, 0, stream>>>(rm, RMT);
  k_zero_f32<<<16, 256, 0, stream>>>(dvec, 4096);

  // A2 = adj @ adj   (4096^3, the big one)
  k_gemm_bt<128, 128, 64, 64, 0><<<dim3(32, 32), 256, 0, stream>>>(
      Abf, ATbf, A2bf, nullptr, nullptr, 4096, 4096, 4096);

  // d[i] = sum_j A2[i,j] * A2[j,i]
  k_diag<<<4096, 256, 0, stream>>>(A2bf, dvec);

  // T1^T = (A2 @ RM)^T   (stored 256 x 4096 bf16)
  k_gemm_bt<64, 64, 32, 32, 1><<<dim3(64, 4), 256, 0, stream>>>(
      A2bf, RMT, T1T, nullptr, nullptr, 4096, 256, 4096);

  // out = A2 @ T1 - d*rm  (fused epilogue)
  k_gemm_bt<64, 64, 32, 32, 2><<<dim3(64, 4), 256, 0, stream>>>(
      A2bf, T1T, out, dvec, rm, 4096, 256, 4096);
}

// Round 2
// 327.446 us; speedup vs baseline: 1.6461x; 1.6461x over previous
//
#include <hip/hip_runtime.h>

// ---------------------------------------------------------------------------
// SGC: out[b,i,f] = sum_{j!=i} (adj^4)[i,j] * rm[b,j,f]
//   A2   = adj @ adj                      (bf16 MFMA, 4096^3, m97-style)
//   T1   = A2 @ RM   (split-K, fp32 partials -> T1T bf16 256x4096)
//   T2   = A2 @ T1   (split-K, fp32 partials -> fused out = T2 - d*rm)
//   d[i] = sum_j A2[i,j]*A2[j,i]
// LDS swizzle: LDS(row, c8) holds G(row, c8 ^ (row&7)) in 16B units so
// global_load_lds (wave-uniform base + lane*16, no padding possible) still
// gives conflict-free ds_read_b128 fragment reads.
// ---------------------------------------------------------------------------

typedef __attribute__((ext_vector_type(8))) __bf16 bf16x8;
typedef __attribute__((ext_vector_type(4))) float floatx4;
typedef __attribute__((ext_vector_type(4))) short short4v;

__device__ __forceinline__ unsigned short f32_to_bf16_bits(float f) {
  unsigned int u = __float_as_uint(f);
  u += 0x7FFFu + ((u >> 16) & 1u);  // RNE
  return (unsigned short)(u >> 16);
}
__device__ __forceinline__ float bf16_bits_to_f32(unsigned short s) {
  return __uint_as_float(((unsigned int)s) << 16);
}

__device__ __forceinline__ void gld_lds16(const unsigned short* g, unsigned short* l) {
  __builtin_amdgcn_global_load_lds(
      (const __attribute__((address_space(1))) void*)g,
      (__attribute__((address_space(3))) void*)l, 16, 0, 0);
}

// --- fused: adj fp32 -> bf16 row-major AND bf16 transposed ------------------
__global__ __launch_bounds__(256) void k_prep_adj(const float* __restrict__ in,
                                                  unsigned short* __restrict__ a,
                                                  unsigned short* __restrict__ at) {
  __shared__ float tile[64][65];
  const int t = threadIdx.x;
  const int row0 = blockIdx.y * 64, col0 = blockIdx.x * 64;
  const int c4 = (t & 15) * 4;
  const int r = t >> 4;
  for (int rr = 0; rr < 64; rr += 16) {
    float4 v = *(const float4*)(in + (size_t)(row0 + r + rr) * 4096 + col0 + c4);
    tile[r + rr][c4 + 0] = v.x;
    tile[r + rr][c4 + 1] = v.y;
    tile[r + rr][c4 + 2] = v.z;
    tile[r + rr][c4 + 3] = v.w;
    short4v s;
    s.x = (short)f32_to_bf16_bits(v.x);
    s.y = (short)f32_to_bf16_bits(v.y);
    s.z = (short)f32_to_bf16_bits(v.z);
    s.w = (short)f32_to_bf16_bits(v.w);
    *(short4v*)(a + (size_t)(row0 + r + rr) * 4096 + col0 + c4) = s;
  }
  __syncthreads();
  for (int rr = 0; rr < 64; rr += 16) {
    const int orow = r + rr;
    short4v s;
    s.x = (short)f32_to_bf16_bits(tile[c4 + 0][orow]);
    s.y = (short)f32_to_bf16_bits(tile[c4 + 1][orow]);
    s.z = (short)f32_to_bf16_bits(tile[c4 + 2][orow]);
    s.w = (short)f32_to_bf16_bits(tile[c4 + 3][orow]);
    *(short4v*)(at + (size_t)(col0 + orow) * 4096 + row0 + c4) = s;
  }
}

// --- RMT[b*32+f][j] = bf16(rm[b,j,f]), tiled for coalescing -----------------
__global__ __launch_bounds__(256) void k_build_rmt(const float* __restrict__ rm,
                                                   unsigned short* __restrict__ rmt) {
  __shared__ unsigned short tile[64][33];
  const int b = blockIdx.x;        // 0..7
  const int j0 = blockIdx.y * 64;  // 64 tiles
  const int t = threadIdx.x;
  #pragma unroll
  for (int p = 0; p < 2; ++p) {
    const int j = (t >> 3) + p * 32;
    const int f4 = (t & 7) * 4;
    float4 v = *(const float4*)(rm + ((size_t)b * 4096 + j0 + j) * 32 + f4);
    tile[j][f4 + 0] = f32_to_bf16_bits(v.x);
    tile[j][f4 + 1] = f32_to_bf16_bits(v.y);
    tile[j][f4 + 2] = f32_to_bf16_bits(v.z);
    tile[j][f4 + 3] = f32_to_bf16_bits(v.w);
  }
  __syncthreads();
  const int f = t >> 3, j8 = (t & 7) * 8;
  unsigned short tmp[8];
  #pragma unroll
  for (int k = 0; k < 8; ++k) tmp[k] = tile[j8 + k][f];
  *(int4*)(rmt + ((size_t)b * 32 + f) * 4096 + j0 + j8) = *(const int4*)tmp;
}

__global__ __launch_bounds__(256) void k_zero_f32(float* __restrict__ p, int n) {
  int i = blockIdx.x * 256 + threadIdx.x;
  if (i < n) p[i] = 0.f;
}

// --- d[i] = sum_j A2[i,j]*A2[j,i] ------------------------------------------
__global__ __launch_bounds__(256) void k_diag(const unsigned short* __restrict__ M2,
                                              float* __restrict__ d) {
  constexpr int P = 72;
  __shared__ __align__(16) unsigned short t1[64 * P];
  __shared__ __align__(16) unsigned short t2[64 * P];
  __shared__ float red[256];
  const int I = blockIdx.x >> 6, J = blockIdx.x & 63;
  const int t = threadIdx.x;
  for (int c = t; c < 512; c += 256) {
    const int row = c >> 3, col = (c & 7) * 8;
    *(int4*)(t1 + row * P + col) =
        *(const int4*)(M2 + (size_t)(I * 64 + row) * 4096 + J * 64 + col);
    *(int4*)(t2 + row * P + col) =
        *(const int4*)(M2 + (size_t)(J * 64 + row) * 4096 + I * 64 + col);
  }
  __syncthreads();
  const int i = t & 63, q = t >> 6;
  float s = 0.f;
  #pragma unroll
  for (int jj = 0; jj < 16; ++jj) {
    const int j = q * 16 + jj;
    s += bf16_bits_to_f32(t1[i * P + j]) * bf16_bits_to_f32(t2[j * P + i]);
  }
  red[t] = s;
  __syncthreads();
  if (t < 64) {
    const float tot = red[t] + red[t + 64] + red[t + 128] + red[t + 192];
    atomicAdd(&d[I * 64 + t], tot);
  }
}

// --- big GEMM: C = A @ BT^T, 128x128 tile, BK=64, global_load_lds + swizzle -
__global__ __launch_bounds__(256) void k_gemm_big(const unsigned short* __restrict__ A,
                                                  const unsigned short* __restrict__ BT,
                                                  unsigned short* __restrict__ C,
                                                  int M, int N, int K) {
  __shared__ __align__(16) unsigned short smA[128 * 64];
  __shared__ __align__(16) unsigned short smB[128 * 64];
  const int tid = threadIdx.x;
  const int wave = tid >> 6, lane = tid & 63;
  const int quad = lane >> 4, l16 = lane & 15;
  const int wm = (wave & 1) * 64, wn = (wave >> 1) * 64;
  const int m0 = blockIdx.x * 128, n0 = blockIdx.y * 128;
  const int srow = lane >> 3;                  // row within 8-row chunk
  const int gcol = ((lane & 7) ^ srow) * 8;    // swizzled global col (elements)

  floatx4 acc[4][4];
  #pragma unroll
  for (int i = 0; i < 4; ++i)
    #pragma unroll
    for (int j = 0; j < 4; ++j) acc[i][j] = floatx4{0.f, 0.f, 0.f, 0.f};

  for (int k0 = 0; k0 < K; k0 += 64) {
    #pragma unroll
    for (int c = 0; c < 4; ++c) {
      const int ch = wave * 4 + c;       // 16 chunks of 1KB each
      const int row = ch * 8 + srow;
      gld_lds16(A + (size_t)(m0 + row) * K + k0 + gcol, smA + ch * 512);
      gld_lds16(BT + (size_t)(n0 + row) * K + k0 + gcol, smB + ch * 512);
    }
    __syncthreads();  // drains vmcnt: staging visible
    #pragma unroll
    for (int kk = 0; kk < 64; kk += 32) {
      const int g8 = quad + (kk >> 3);
      bf16x8 af[4], bfr[4];
      #pragma unroll
      for (int i = 0; i < 4; ++i) {
        const int row = wm + i * 16 + l16;
        af[i] = *(const bf16x8*)(smA + row * 64 + ((g8 ^ (row & 7)) * 8));
      }
      #pragma unroll
      for (int j = 0; j < 4; ++j) {
        const int row = wn + j * 16 + l16;
        bfr[j] = *(const bf16x8*)(smB + row * 64 + ((g8 ^ (row & 7)) * 8));
      }
      #pragma unroll
      for (int i = 0; i < 4; ++i)
        #pragma unroll
        for (int j = 0; j < 4; ++j)
          acc[i][j] = __builtin_amdgcn_mfma_f32_16x16x32_bf16(af[i], bfr[j],
                                                              acc[i][j], 0, 0, 0);
    }
    __syncthreads();  // compute done before next staging overwrite
  }
  #pragma unroll
  for (int i = 0; i < 4; ++i) {
    #pragma unroll
    for (int j = 0; j < 4; ++j) {
      const int rowb = m0 + wm + i * 16 + quad * 4;
      const int col = n0 + wn + j * 16 + l16;
      #pragma unroll
      for (int r = 0; r < 4; ++r)
        C[(size_t)(rowb + r) * N + col] = f32_to_bf16_bits(acc[i][j][r]);
    }
  }
}

// --- skinny split-K GEMM: BM=64, BN=256(=N), KC per block; fp32 partials ----
template <int KC>
__global__ __launch_bounds__(256) void k_gemm_skinny(const unsigned short* __restrict__ A,
                                                     const unsigned short* __restrict__ BT,
                                                     float* __restrict__ P, int K) {
  __shared__ __align__(16) unsigned short smA[64 * 64];
  __shared__ __align__(16) unsigned short smB[256 * 64];
  const int tid = threadIdx.x;
  const int wave = tid >> 6, lane = tid & 63;
  const int quad = lane >> 4, l16 = lane & 15;
  const int m0 = blockIdx.x * 64;
  const int kt = blockIdx.y;
  const int wn = wave * 64;
  const int srow = lane >> 3;
  const int gcol = ((lane & 7) ^ srow) * 8;

  floatx4 acc[4][4];
  #pragma unroll
  for (int i = 0; i < 4; ++i)
    #pragma unroll
    for (int j = 0; j < 4; ++j) acc[i][j] = floatx4{0.f, 0.f, 0.f, 0.f};

  for (int k0 = kt * KC; k0 < kt * KC + KC; k0 += 64) {
    #pragma unroll
    for (int u = 0; u < 10; ++u) {
      const int ch = wave * 10 + u;  // 8 A-chunks + 32 B-chunks
      if (ch < 8) {
        const int row = ch * 8 + srow;
        gld_lds16(A + (size_t)(m0 + row) * K + k0 + gcol, smA + ch * 512);
      } else {
        const int c2 = ch - 8;
        const int row = c2 * 8 + srow;
        gld_lds16(BT + (size_t)row * K + k0 + gcol, smB + c2 * 512);
      }
    }
    __syncthreads();
    #pragma unroll
    for (int kk = 0; kk < 64; kk += 32) {
      const int g8 = quad + (kk >> 3);
      bf16x8 af[4], bfr[4];
      #pragma unroll
      for (int i = 0; i < 4; ++i) {
        const int row = i * 16 + l16;
        af[i] = *(const bf16x8*)(smA + row * 64 + ((g8 ^ (row & 7)) * 8));
      }
      #pragma unroll
      for (int j = 0; j < 4; ++j) {
        const int row = wn + j * 16 + l16;
        bfr[j] = *(const bf16x8*)(smB + row * 64 + ((g8 ^ (row & 7)) * 8));
      }
      #pragma unroll
      for (int i = 0; i < 4; ++i)
        #pragma unroll
        for (int j = 0; j < 4; ++j)
          acc[i][j] = __builtin_amdgcn_mfma_f32_16x16x32_bf16(af[i], bfr[j],
                                                              acc[i][j], 0, 0, 0);
    }
    __syncthreads();
  }
  #pragma unroll
  for (int i = 0; i < 4; ++i) {
    #pragma unroll
    for (int j = 0; j < 4; ++j) {
      const int rowl = i * 16 + quad * 4;
      const int col = wn + j * 16 + l16;
      #pragma unroll
      for (int r = 0; r < 4; ++r)
        P[((size_t)kt * 4096 + m0 + rowl + r) * 256 + col] = acc[i][j][r];
    }
  }
}

// --- reduce partials -> T1T bf16 (transposed 256 x 4096) --------------------
__global__ __launch_bounds__(256) void k_reduce_t1t(const float* __restrict__ P,
                                                    unsigned short* __restrict__ T1T) {
  __shared__ float tile[64][65];
  const int mt = blockIdx.x, nt = blockIdx.y;
  const int t = threadIdx.x;
  #pragma unroll
  for (int e = 0; e < 16; ++e) {
    const int idx = e * 256 + t;
    const int r = idx >> 6, c = idx & 63;
    float s = 0.f;
    #pragma unroll
    for (int kt = 0; kt < 8; ++kt)
      s += P[(size_t)kt * 1048576 + (size_t)(mt * 64 + r) * 256 + nt * 64 + c];
    tile[r][c] = s;
  }
  __syncthreads();
  const int nr = t >> 2, mq = (t & 3) * 16;
  unsigned short tmp[16];
  #pragma unroll
  for (int k = 0; k < 16; ++k) tmp[k] = f32_to_bf16_bits(tile[mq + k][nr]);
  unsigned short* dst = T1T + (size_t)(nt * 64 + nr) * 4096 + mt * 64 + mq;
  *(int4*)(dst) = *(const int4*)(tmp);
  *(int4*)(dst + 8) = *(const int4*)(tmp + 8);
}

// --- reduce partials + fused epilogue: out = sum P - d[row]*rm --------------
__global__ __launch_bounds__(256) void k_reduce_out(const float* __restrict__ P,
                                                    const float* __restrict__ dvec,
                                                    const float* __restrict__ rm,
                                                    float* __restrict__ out) {
  const int idx = blockIdx.x * 256 + threadIdx.x;  // row*256+col
  const int row = idx >> 8, col = idx & 255;
  float s = 0.f;
  #pragma unroll
  for (int kt = 0; kt < 8; ++kt) s += P[(size_t)kt * 1048576 + idx];
  const int b = col >> 5, f = col & 31;
  const size_t o = ((size_t)b * 4096 + row) * 32 + f;
  out[o] = s - dvec[row] * rm[o];
}

extern "C" void kernel_launch(void* const* d_in, const int* in_sizes, int n_in,
                              void* d_out, int out_size, void* d_ws, size_t ws_size,
                              hipStream_t stream) {
  const float* rm = (const float*)d_in[0];   // (8, 4096, 32) fp32
  const float* adj = (const float*)d_in[1];  // (4096, 4096) fp32
  float* out = (float*)d_out;
  char* ws = (char*)d_ws;

  unsigned short* Abf  = (unsigned short*)(ws);              // 32 MiB (dies after big GEMM)
  unsigned short* ATbf = (unsigned short*)(ws + 33554432);   // 32 MiB (dies after big GEMM)
  unsigned short* A2bf = (unsigned short*)(ws + 67108864);   // 32 MiB
  unsigned short* RMT  = (unsigned short*)(ws + 100663296);  // 2 MiB
  unsigned short* T1T  = (unsigned short*)(ws + 102760448);  // 2 MiB
  float* dvec          = (float*)(ws + 104857600);           // 16 KiB
  float* Ppart         = (float*)(ws);                       // 32 MiB, reuses Abf region

  k_prep_adj<<<dim3(64, 64), 256, 0, stream>>>(adj, Abf, ATbf);
  k_build_rmt<<<dim3(8, 64), 256, 0, stream>>>(rm, RMT);
  k_zero_f32<<<16, 256, 0, stream>>>(dvec, 4096);

  // A2 = adj @ adj
  k_gemm_big<<<dim3(32, 32), 256, 0, stream>>>(Abf, ATbf, A2bf, 4096, 4096, 4096);

  // d[i] = sum_j A2[i,j] * A2[j,i]
  k_diag<<<4096, 256, 0, stream>>>(A2bf, dvec);

  // T1 = A2 @ RM  (split-K partials -> T1T bf16)
  k_gemm_skinny<512><<<dim3(64, 8), 256, 0, stream>>>(A2bf, RMT, Ppart, 4096);
  k_reduce_t1t<<<dim3(64, 4), 256, 0, stream>>>(Ppart, T1T);

  // T2 = A2 @ T1  (split-K partials -> fused out = T2 - d*rm)
  k_gemm_skinny<512><<<dim3(64, 8), 256, 0, stream>>>(A2bf, T1T, Ppart, 4096);
  k_reduce_out<<<4096, 256, 0, stream>>>(Ppart, dvec, rm, out);
}